// Round 2
// baseline (1297.349 us; speedup 1.0000x reference)
//
#include <hip/hip_runtime.h>
#include <cstddef>

#define THRESH 0.1f

constexpr int Bn = 8, C = 256, H = 128, W = 128;
constexpr int HW = H * W;
constexpr size_t CHW = (size_t)C * HW;
constexpr int WSZ = 9 * 256 * 256;          // elements per transformed weight
constexpr int SA_ELEM = 4 * 132 * 32;       // 16896 elements per LDS buffer
constexpr int SA_BYTES = 2 * SA_ELEM * 2;   // 67584 B (double-buffered)

typedef __attribute__((ext_vector_type(8))) short short8;   // 8 bf16
typedef __attribute__((ext_vector_type(4))) float f32x4;

__device__ __forceinline__ float bf2f(ushort u) {
    union { unsigned u; float f; } v; v.u = ((unsigned)u) << 16; return v.f;
}
__device__ __forceinline__ ushort f2bf(float f) {
    union { float f; unsigned u; } v; v.f = f;
    unsigned r = v.u + 0x7FFF + ((v.u >> 16) & 1);   // RNE
    return (ushort)(r >> 16);
}
__device__ __forceinline__ float pm(float x, float a) {
    float t = (x >= 0.f) ? x : a * x;                 // prelu
    return (fabsf(t) >= THRESH) ? t : 0.f;            // NaNConv input mask
}

// async global->LDS, 16 B per lane; LDS side is wave-uniform base + lane*16
__device__ __forceinline__ void load_lds16(const void* g, void* l) {
    __builtin_amdgcn_global_load_lds(
        (const __attribute__((address_space(1))) unsigned int*)g,
        (__attribute__((address_space(3))) unsigned int*)l, 16, 0, 0);
}

// ---------------------------------------------------------------------------
// Weight transform: fp32 [co][ci][3][3] -> bf16 fragment-major
// [co>>6][ci>>5][tap][mfrag][lane64][8]   (lane = (co&15) + 16*((ci>>3)&3))
__global__ void wtrans_kernel(const float* __restrict__ w1,
                              const float* __restrict__ w2,
                              const float* __restrict__ w3,
                              ushort* __restrict__ Wtf)
{
    const float* src = (blockIdx.z == 0) ? w1 : (blockIdx.z == 1) ? w2 : w3;
    ushort* dst = Wtf + (size_t)blockIdx.z * WSZ;
    int idx = blockIdx.x * 256 + threadIdx.x;   // 0..65535 = co*256+ci
    int co = idx >> 8, ci = idx & 255;
    int cb  = co >> 6;
    int m   = (co >> 4) & 3;
    int l15 = co & 15;
    int cib = ci >> 5;
    int l4  = (ci >> 3) & 3;
    int j   = ci & 7;
    int lane = l15 + 16 * l4;
    for (int t = 0; t < 9; ++t) {
        float v = src[((size_t)co * 256 + ci) * 9 + t];
        size_t o = ((((size_t)cb * 8 + cib) * 9 + t) * 4 + m) * 512 + lane * 8 + j;
        dst[o] = f2bf(v);
    }
}

// ---------------------------------------------------------------------------
// x (fp32 NCHW) -> Xt (bf16 NHWC) with pm applied.  grid (4, 128, 8)
__global__ __launch_bounds__(256) void xt1_kernel(const float* __restrict__ x,
                                                  const float* __restrict__ pa,
                                                  ushort* __restrict__ Xt)
{
    __shared__ float sl[64][133];
    int tid = threadIdx.x;
    int ci0 = blockIdx.x * 64, h = blockIdx.y, b = blockIdx.z;
    float a = pa[0];
    int wcol = tid & 127, chalf = tid >> 7;
    const float* xb = x + (size_t)b * CHW + (size_t)ci0 * HW + h * W;
    for (int r = 0; r < 32; ++r) {
        int ci = r * 2 + chalf;
        sl[ci][wcol] = pm(xb[(size_t)ci * HW + wcol], a);
    }
    __syncthreads();
    ushort* dst = Xt + ((size_t)(b * H + h)) * W * C + ci0;
    for (int r = 0; r < 4; ++r) {
        int c = r * 256 + tid;
        int wc = c >> 3, cic = c & 7;
        unsigned p0 = f2bf(sl[cic*8+0][wc]) | ((unsigned)f2bf(sl[cic*8+1][wc]) << 16);
        unsigned p1 = f2bf(sl[cic*8+2][wc]) | ((unsigned)f2bf(sl[cic*8+3][wc]) << 16);
        unsigned p2 = f2bf(sl[cic*8+4][wc]) | ((unsigned)f2bf(sl[cic*8+5][wc]) << 16);
        unsigned p3 = f2bf(sl[cic*8+6][wc]) | ((unsigned)f2bf(sl[cic*8+7][wc]) << 16);
        uint4 v = {p0, p1, p2, p3};
        *(uint4*)(dst + (size_t)wc * C + cic * 8) = v;
    }
}

// ---------------------------------------------------------------------------
// Implicit-GEMM 3x3 conv, bf16 MFMA, fused epilogue, 2-phase LDS pipeline.
// Block: 64 co x (2 h-rows x 128 w) = 64 x 256 GEMM tile, 4 waves.
// Wave: 4 mfrag x 4 nfrag of 16x16x32; wave wv -> hrow = wv>>1, whalf = wv&1.
// Activations: global_load_lds into sa[buf][r4][wi132][chunk4][8ci], chunk
// XOR-swizzled by ((row>>1)&3) via pre-swizzled GLOBAL source (dest linear).
// Pipeline: double-buffered sa; issue stage(cib+1) BEFORE compute(cib); raw
// s_barrier + explicit vmcnt(0) so loads stay in flight across compute.
// Weights: A-frags read directly from global (L2-resident, fragment-major).
// grid 1D 2048, XCD-chunked swizzle: each XCD owns contiguous by-range, cb fastest.
//
// MODE 0: out fp32 NCHW = acc + bias                      (conv3)
// MODE 1: m = max(x_f32, acc+bias); xmax(NHWC)=m; XtOut=pm(m)   (conv1 + maxt1)
// MODE 2: m = max(acc+bias, xmax(NHWC)); XtOut=pm(m)            (conv2 + maxt2)
template <int MODE>
__global__ __launch_bounds__(256, 2) void conv_kernel(
    const ushort* __restrict__ Xt, const ushort* __restrict__ Wtf,
    const float* __restrict__ bias, const float* __restrict__ pa,
    const float* __restrict__ xf,      // MODE 1: original x, fp32 NCHW
    ushort* __restrict__ xmax,         // MODE 1: write NHWC; MODE 2: read NHWC
    ushort* __restrict__ XtOut,        // MODE 1/2: next-layer input, NHWC pm'd
    float* __restrict__ out)           // MODE 0
{
    extern __shared__ __align__(16) ushort sa[];   // 2 x 16896 elements

    const int tid = threadIdx.x, lane = tid & 63, wv = tid >> 6;
    // XCD-chunked bijective swizzle (2048 % 8 == 0)
    const int orig = blockIdx.x;
    const int vid = (orig & 7) * 256 + (orig >> 3);
    const int cb = vid & 3, by = vid >> 2;
    const int co0 = cb * 64;
    const int b = by >> 6, h0 = (by & 63) * 2;
    const int l15 = lane & 15, l4 = lane >> 4;
    const int hrow = wv >> 1, whalf = wv & 1;

    // zero both buffers once; OOB rows / halo chunks are never overwritten
    {
        uint4 z = {0, 0, 0, 0};
        uint4* zp = (uint4*)sa;
        for (int i = tid; i < 4224; i += 256) zp[i] = z;
    }
    __syncthreads();

    f32x4 acc[4][4];
    const f32x4 z4 = {0.f, 0.f, 0.f, 0.f};
#pragma unroll
    for (int m = 0; m < 4; ++m)
#pragma unroll
        for (int n = 0; n < 4; ++n) acc[m][n] = z4;

    const ushort* xb = Xt + (size_t)b * H * W * C;
    // this wave stages row sr (hh = h0-1+sr); lane l -> w-chunk seg*16+(l>>2), 16B quarter l&3
    const int sr = wv;
    const int shh = h0 - 1 + sr;
    const bool svalid = (unsigned)shh < 128u;
    const ushort* sgbase = xb + (size_t)shh * W * C;
    const int lchunk = lane >> 2, lsub = lane & 3;

    auto stage = [&](int buf, int ci0) {
        ushort* slb = sa + buf * SA_ELEM + (sr * 132 + 1) * 32;
#pragma unroll
        for (int seg = 0; seg < 8; ++seg) {
            int ww = seg * 16 + lchunk;   // 0..127
            // chunk swizzle key from row-in-buffer (sr*132 + 1 + ww);
            // LDS dest linear, so permute which global 16B this lane fetches
            int key = ((sr * 132 + 1 + ww) >> 1) & 3;
            const void* gp = sgbase + (size_t)ww * C + ci0 + ((lsub ^ key) << 3);
            load_lds16(gp, slb + seg * 512);   // 512 ushort = 16 chunks
        }
    };

    // prologue: tile 0 -> buf 0, full drain
    if (svalid) stage(0, 0);
    asm volatile("s_waitcnt vmcnt(0)" ::: "memory");
    __builtin_amdgcn_s_barrier();
    __builtin_amdgcn_sched_barrier(0);

    for (int cib = 0; cib < 8; ++cib) {
        const int cur = cib & 1;
        // issue next tile's loads; they stay in flight across this compute
        if (cib < 7 && svalid) stage(cur ^ 1, (cib + 1) * 32);

        const ushort* scur = sa + cur * SA_ELEM;
        const ushort* wB = Wtf + ((size_t)cb * 8 + cib) * 18432;  // 9 taps x 4 m x 512
#pragma unroll
        for (int ky = 0; ky < 3; ++ky) {
            const int r = hrow + ky;
#pragma unroll
            for (int kx = 0; kx < 3; ++kx) {
                const int t = ky * 3 + kx;
                short8 af[4], bfv[4];
#pragma unroll
                for (int m = 0; m < 4; ++m)
                    af[m] = *(const short8*)(wB + (size_t)(t * 4 + m) * 512 + lane * 8);
#pragma unroll
                for (int n = 0; n < 4; ++n) {
                    int wi = whalf * 64 + n * 16 + l15 + kx;      // 0..129
                    int row = r * 132 + wi;
                    int key = (row >> 1) & 3;                      // matches write side
                    bfv[n] = *(const short8*)(scur + row * 32 + ((l4 ^ key) << 3));
                }
#pragma unroll
                for (int m = 0; m < 4; ++m)
#pragma unroll
                    for (int n = 0; n < 4; ++n)
                        acc[m][n] = __builtin_amdgcn_mfma_f32_16x16x32_bf16(
                            af[m], bfv[n], acc[m][n], 0, 0, 0);
            }
        }
        // wait this iteration's prefetch (had whole compute phase to land),
        // then release buffers; raw barrier avoids compiler's full pre-drain
        asm volatile("s_waitcnt vmcnt(0)" ::: "memory");
        __builtin_amdgcn_s_barrier();
        __builtin_amdgcn_sched_barrier(0);
    }

    // epilogue: D row = l4*4+rr (co), col = l15 (w)
    const int h = h0 + hrow;
    const float ap = (MODE != 0) ? pa[0] : 0.f;
#pragma unroll
    for (int m = 0; m < 4; ++m) {
        const int cobase = co0 + m * 16 + l4 * 4;
        const f32x4 bv = *(const f32x4*)(bias + cobase);
#pragma unroll
        for (int n = 0; n < 4; ++n) {
            const int wc = whalf * 64 + n * 16 + l15;
            if constexpr (MODE == 0) {
#pragma unroll
                for (int rr = 0; rr < 4; ++rr)
                    out[((size_t)(b * C + cobase + rr) * H + h) * W + wc] =
                        acc[m][n][rr] + bv[rr];
            } else {
                const size_t nb = ((size_t)(b * H + h) * W + wc) * C + cobase;
                float mm[4];
                if constexpr (MODE == 1) {
#pragma unroll
                    for (int rr = 0; rr < 4; ++rr) {
                        float vv = acc[m][n][rr] + bv[rr];
                        float xv = xf[((size_t)(b * C + cobase + rr) * H + h) * W + wc];
                        mm[rr] = fmaxf(xv, vv);
                    }
                    uint2 um = {(unsigned)f2bf(mm[0]) | ((unsigned)f2bf(mm[1]) << 16),
                                (unsigned)f2bf(mm[2]) | ((unsigned)f2bf(mm[3]) << 16)};
                    *(uint2*)(xmax + nb) = um;
                } else {
                    uint2 mv = *(const uint2*)(xmax + nb);
                    mm[0] = fmaxf(acc[m][n][0] + bv[0], bf2f((ushort)(mv.x & 0xffffu)));
                    mm[1] = fmaxf(acc[m][n][1] + bv[1], bf2f((ushort)(mv.x >> 16)));
                    mm[2] = fmaxf(acc[m][n][2] + bv[2], bf2f((ushort)(mv.y & 0xffffu)));
                    mm[3] = fmaxf(acc[m][n][3] + bv[3], bf2f((ushort)(mv.y >> 16)));
                }
                uint2 px = {(unsigned)f2bf(pm(mm[0], ap)) | ((unsigned)f2bf(pm(mm[1], ap)) << 16),
                            (unsigned)f2bf(pm(mm[2], ap)) | ((unsigned)f2bf(pm(mm[3], ap)) << 16)};
                *(uint2*)(XtOut + nb) = px;
            }
        }
    }
}

// ---------------------------------------------------------------------------
extern "C" void kernel_launch(void* const* d_in, const int* in_sizes, int n_in,
                              void* d_out, int out_size, void* d_ws, size_t ws_size,
                              hipStream_t stream)
{
    const float* x  = (const float*)d_in[0];
    const float* w1 = (const float*)d_in[1];
    const float* b1 = (const float*)d_in[2];
    const float* w2 = (const float*)d_in[3];
    const float* b2 = (const float*)d_in[4];
    const float* w3 = (const float*)d_in[5];
    const float* b3 = (const float*)d_in[6];
    const float* pa = (const float*)d_in[7];

    char* ws = (char*)d_ws;
    ushort* Xt1  = (ushort*)ws;                       // 67108864 B (bf16 NHWC)
    ushort* Xt2  = (ushort*)(ws + 67108864);          // 67108864 B (bf16 NHWC)
    ushort* xmax = (ushort*)(ws + 134217728);         // 67108864 B (bf16 NHWC)
    ushort* Wtf  = (ushort*)(ws + 201326592);         // 3 x 1179648 B

    // opt-in to >64KB dynamic LDS for the conv kernels (once per process)
    static bool attr_done = false;
    if (!attr_done) {
        hipFuncSetAttribute((const void*)conv_kernel<0>,
                            hipFuncAttributeMaxDynamicSharedMemorySize, SA_BYTES);
        hipFuncSetAttribute((const void*)conv_kernel<1>,
                            hipFuncAttributeMaxDynamicSharedMemorySize, SA_BYTES);
        hipFuncSetAttribute((const void*)conv_kernel<2>,
                            hipFuncAttributeMaxDynamicSharedMemorySize, SA_BYTES);
        attr_done = true;
    }

    dim3 tg(4, 128, 8), tb(256);

    wtrans_kernel<<<dim3(256, 1, 3), 256, 0, stream>>>(w1, w2, w3, Wtf);
    // Xt1 = pm(x)  (NHWC bf16)
    xt1_kernel<<<tg, tb, 0, stream>>>(x, pa, Xt1);
    // conv1 + fused max/prelu/mask/transpose: xmax = max(x, conv1), Xt2 = pm(xmax)
    conv_kernel<1><<<dim3(2048), tb, SA_BYTES, stream>>>(Xt1, Wtf, b1, pa, x, xmax, Xt2, nullptr);
    // conv2 + fused: Xt1 (dead, reused) = pm(max(conv2, xmax))
    conv_kernel<2><<<dim3(2048), tb, SA_BYTES, stream>>>(Xt2, Wtf + WSZ, b2, pa, nullptr, xmax, Xt1, nullptr);
    // conv3 -> fp32 out
    conv_kernel<0><<<dim3(2048), tb, SA_BYTES, stream>>>(Xt1, Wtf + 2 * WSZ, b3, pa, nullptr, nullptr, nullptr, (float*)d_out);
}

// Round 3
// 667.455 us; speedup vs baseline: 1.9437x; 1.9437x over previous
//
#include <hip/hip_runtime.h>
#include <cstddef>

#define THRESH 0.1f

constexpr int Bn = 8, C = 256, H = 128, W = 128;
constexpr int HW = H * W;
constexpr size_t CHW = (size_t)C * HW;
constexpr int WSZ = 9 * 256 * 256;          // elements per transformed weight
constexpr int WT_ELEM = 18432;              // weight tile elements per cib (36864 B)
constexpr int ACT_ELEM = 4 * 132 * 32;      // activation tile elements (33792 B)
constexpr int SA_BYTES = (WT_ELEM + ACT_ELEM) * 2;   // 70656 B

typedef __attribute__((ext_vector_type(8))) short short8;   // 8 bf16
typedef __attribute__((ext_vector_type(4))) float f32x4;

__device__ __forceinline__ float bf2f(ushort u) {
    union { unsigned u; float f; } v; v.u = ((unsigned)u) << 16; return v.f;
}
__device__ __forceinline__ ushort f2bf(float f) {
    union { float f; unsigned u; } v; v.f = f;
    unsigned r = v.u + 0x7FFF + ((v.u >> 16) & 1);   // RNE
    return (ushort)(r >> 16);
}
__device__ __forceinline__ float pm(float x, float a) {
    float t = (x >= 0.f) ? x : a * x;                 // prelu
    return (fabsf(t) >= THRESH) ? t : 0.f;            // NaNConv input mask
}

// async global->LDS, 16 B per lane; LDS side is wave-uniform base + lane*16
__device__ __forceinline__ void load_lds16(const void* g, void* l) {
    __builtin_amdgcn_global_load_lds(
        (const __attribute__((address_space(1))) unsigned int*)g,
        (__attribute__((address_space(3))) unsigned int*)l, 16, 0, 0);
}

// ---------------------------------------------------------------------------
// Weight transform: fp32 [co][ci][3][3] -> bf16 fragment-major
// [co>>6][ci>>5][tap][mfrag][lane64][8]   (lane = (co&15) + 16*((ci>>3)&3))
__global__ void wtrans_kernel(const float* __restrict__ w1,
                              const float* __restrict__ w2,
                              const float* __restrict__ w3,
                              ushort* __restrict__ Wtf)
{
    const float* src = (blockIdx.z == 0) ? w1 : (blockIdx.z == 1) ? w2 : w3;
    ushort* dst = Wtf + (size_t)blockIdx.z * WSZ;
    int idx = blockIdx.x * 256 + threadIdx.x;   // 0..65535 = co*256+ci
    int co = idx >> 8, ci = idx & 255;
    int cb  = co >> 6;
    int m   = (co >> 4) & 3;
    int l15 = co & 15;
    int cib = ci >> 5;
    int l4  = (ci >> 3) & 3;
    int j   = ci & 7;
    int lane = l15 + 16 * l4;
    for (int t = 0; t < 9; ++t) {
        float v = src[((size_t)co * 256 + ci) * 9 + t];
        size_t o = ((((size_t)cb * 8 + cib) * 9 + t) * 4 + m) * 512 + lane * 8 + j;
        dst[o] = f2bf(v);
    }
}

// ---------------------------------------------------------------------------
// x (fp32 NCHW) -> Xt (bf16 NHWC) with pm applied.  grid (4, 128, 8)
__global__ __launch_bounds__(256) void xt1_kernel(const float* __restrict__ x,
                                                  const float* __restrict__ pa,
                                                  ushort* __restrict__ Xt)
{
    __shared__ float sl[64][133];
    int tid = threadIdx.x;
    int ci0 = blockIdx.x * 64, h = blockIdx.y, b = blockIdx.z;
    float a = pa[0];
    int wcol = tid & 127, chalf = tid >> 7;
    const float* xb = x + (size_t)b * CHW + (size_t)ci0 * HW + h * W;
    for (int r = 0; r < 32; ++r) {
        int ci = r * 2 + chalf;
        sl[ci][wcol] = pm(xb[(size_t)ci * HW + wcol], a);
    }
    __syncthreads();
    ushort* dst = Xt + ((size_t)(b * H + h)) * W * C + ci0;
    for (int r = 0; r < 4; ++r) {
        int c = r * 256 + tid;
        int wc = c >> 3, cic = c & 7;
        unsigned p0 = f2bf(sl[cic*8+0][wc]) | ((unsigned)f2bf(sl[cic*8+1][wc]) << 16);
        unsigned p1 = f2bf(sl[cic*8+2][wc]) | ((unsigned)f2bf(sl[cic*8+3][wc]) << 16);
        unsigned p2 = f2bf(sl[cic*8+4][wc]) | ((unsigned)f2bf(sl[cic*8+5][wc]) << 16);
        unsigned p3 = f2bf(sl[cic*8+6][wc]) | ((unsigned)f2bf(sl[cic*8+7][wc]) << 16);
        uint4 v = {p0, p1, p2, p3};
        *(uint4*)(dst + (size_t)wc * C + cic * 8) = v;
    }
}

// ---------------------------------------------------------------------------
// Implicit-GEMM 3x3 conv, bf16 MFMA, fused epilogue.
// Block: 64 co x (2 h-rows x 128 w) = 64 x 256 GEMM tile, 4 waves.
// Wave: 4 mfrag x 4 nfrag of 16x16x32; wave wv -> hrow = wv>>1, whalf = wv&1.
// LDS: [weights WT_ELEM | activations ACT_ELEM], both staged via global_load_lds.
//   Weights (fragment-major, linear): staged once per block per cib -> each
//   wave ds_reads A-frags from LDS instead of 4x-refetching 36KB from L2.
//   Activations: sa_act[r4][wi132][chunk4][8ci], chunk XOR-swizzled by
//   ((row>>1)&3) via pre-swizzled GLOBAL source (LDS dest stays linear).
// Barrier structure = round-1 (syncthreads, compiler-managed waits): the
// compute phase is now LDS-only, so the barrier drain covers staging only.
// grid 1D 2048, XCD-chunked swizzle: each XCD owns contiguous by-range, cb fastest.
//
// MODE 0: out fp32 NCHW = acc + bias                      (conv3)
// MODE 1: m = max(x_f32, acc+bias); xmax(NHWC)=m; XtOut=pm(m)   (conv1 + maxt1)
// MODE 2: m = max(acc+bias, xmax(NHWC)); XtOut=pm(m)            (conv2 + maxt2)
template <int MODE>
__global__ __launch_bounds__(256, 2) void conv_kernel(
    const ushort* __restrict__ Xt, const ushort* __restrict__ Wtf,
    const float* __restrict__ bias, const float* __restrict__ pa,
    const float* __restrict__ xf,      // MODE 1: original x, fp32 NCHW
    ushort* __restrict__ xmax,         // MODE 1: write NHWC; MODE 2: read NHWC
    ushort* __restrict__ XtOut,        // MODE 1/2: next-layer input, NHWC pm'd
    float* __restrict__ out)           // MODE 0
{
    extern __shared__ __align__(16) ushort sa[];   // [WT_ELEM | ACT_ELEM]
    ushort* sw = sa;                   // weights, base 0 -> ds imm offsets fold
    ushort* sact = sa + WT_ELEM;

    const int tid = threadIdx.x, lane = tid & 63, wv = tid >> 6;
    // XCD-chunked bijective swizzle (2048 % 8 == 0)
    const int orig = blockIdx.x;
    const int vid = (orig & 7) * 256 + (orig >> 3);
    const int cb = vid & 3, by = vid >> 2;
    const int co0 = cb * 64;
    const int b = by >> 6, h0 = (by & 63) * 2;
    const int l15 = lane & 15, l4 = lane >> 4;
    const int hrow = wv >> 1, whalf = wv & 1;

    // zero activation region once; OOB rows / halo chunks are never overwritten
    {
        uint4 z = {0, 0, 0, 0};
        uint4* zp = (uint4*)sact;
        for (int i = tid; i < ACT_ELEM / 8; i += 256) zp[i] = z;
    }

    f32x4 acc[4][4];
    const f32x4 z4 = {0.f, 0.f, 0.f, 0.f};
#pragma unroll
    for (int m = 0; m < 4; ++m)
#pragma unroll
        for (int n = 0; n < 4; ++n) acc[m][n] = z4;

    const ushort* xb = Xt + (size_t)b * H * W * C;
    // this wave stages act row sr (hh = h0-1+sr); lane l -> w-chunk seg*16+(l>>2)
    const int sr = wv;
    const int shh = h0 - 1 + sr;
    const bool svalid = (unsigned)shh < 128u;
    const ushort* sgbase = xb + (size_t)shh * W * C;
    const int lchunk = lane >> 2, lsub = lane & 3;

    for (int cib = 0; cib < 8; ++cib) {
        const int ci0 = cib * 32;
        __syncthreads();                      // prev cib's LDS reads complete
        // stage weight tile: 2304 chunks of 16B; wave wv owns chunks
        // [wv*576, wv*576+576), 9 groups of 64 (lane offset added by HW)
        {
            const ushort* wsrc = Wtf + ((size_t)cb * 8 + cib) * WT_ELEM;
#pragma unroll
            for (int g = 0; g < 9; ++g) {
                int ch = wv * 576 + g * 64;
                load_lds16(wsrc + (size_t)(ch + lane) * 8, sw + (size_t)ch * 8);
            }
        }
        if (svalid) {
#pragma unroll
            for (int seg = 0; seg < 8; ++seg) {
                int ww = seg * 16 + lchunk;   // 0..127
                // chunk swizzle key from row index (sr*132 + 1 + ww);
                // LDS dest linear, so permute which global 16B this lane fetches
                int key = ((sr * 132 + 1 + ww) >> 1) & 3;
                const void* gp = sgbase + (size_t)ww * C + ci0 + ((lsub ^ key) << 3);
                load_lds16(gp, sact + (sr * 132 + 1) * 32 + seg * 512);
            }
        }
        __syncthreads();                      // staging visible (vmcnt drained)

#pragma unroll
        for (int ky = 0; ky < 3; ++ky) {
            const int r = hrow + ky;
#pragma unroll
            for (int kx = 0; kx < 3; ++kx) {
                const int t = ky * 3 + kx;
                short8 af[4], bfv[4];
#pragma unroll
                for (int m = 0; m < 4; ++m)
                    af[m] = *(const short8*)(sw + (size_t)(t * 4 + m) * 512 + lane * 8);
#pragma unroll
                for (int n = 0; n < 4; ++n) {
                    int wi = whalf * 64 + n * 16 + l15 + kx;      // 0..129
                    int row = r * 132 + wi;
                    int key = (row >> 1) & 3;                      // matches write side
                    bfv[n] = *(const short8*)(sact + row * 32 + ((l4 ^ key) << 3));
                }
#pragma unroll
                for (int m = 0; m < 4; ++m)
#pragma unroll
                    for (int n = 0; n < 4; ++n)
                        acc[m][n] = __builtin_amdgcn_mfma_f32_16x16x32_bf16(
                            af[m], bfv[n], acc[m][n], 0, 0, 0);
            }
        }
    }

    // epilogue: D row = l4*4+rr (co), col = l15 (w)
    const int h = h0 + hrow;
    const float ap = (MODE != 0) ? pa[0] : 0.f;
#pragma unroll
    for (int m = 0; m < 4; ++m) {
        const int cobase = co0 + m * 16 + l4 * 4;
        const f32x4 bv = *(const f32x4*)(bias + cobase);
#pragma unroll
        for (int n = 0; n < 4; ++n) {
            const int wc = whalf * 64 + n * 16 + l15;
            if constexpr (MODE == 0) {
#pragma unroll
                for (int rr = 0; rr < 4; ++rr)
                    out[((size_t)(b * C + cobase + rr) * H + h) * W + wc] =
                        acc[m][n][rr] + bv[rr];
            } else {
                const size_t nb = ((size_t)(b * H + h) * W + wc) * C + cobase;
                float mm[4];
                if constexpr (MODE == 1) {
#pragma unroll
                    for (int rr = 0; rr < 4; ++rr) {
                        float vv = acc[m][n][rr] + bv[rr];
                        float xv = xf[((size_t)(b * C + cobase + rr) * H + h) * W + wc];
                        mm[rr] = fmaxf(xv, vv);
                    }
                    uint2 um = {(unsigned)f2bf(mm[0]) | ((unsigned)f2bf(mm[1]) << 16),
                                (unsigned)f2bf(mm[2]) | ((unsigned)f2bf(mm[3]) << 16)};
                    *(uint2*)(xmax + nb) = um;
                } else {
                    uint2 mv = *(const uint2*)(xmax + nb);
                    mm[0] = fmaxf(acc[m][n][0] + bv[0], bf2f((ushort)(mv.x & 0xffffu)));
                    mm[1] = fmaxf(acc[m][n][1] + bv[1], bf2f((ushort)(mv.x >> 16)));
                    mm[2] = fmaxf(acc[m][n][2] + bv[2], bf2f((ushort)(mv.y & 0xffffu)));
                    mm[3] = fmaxf(acc[m][n][3] + bv[3], bf2f((ushort)(mv.y >> 16)));
                }
                uint2 px = {(unsigned)f2bf(pm(mm[0], ap)) | ((unsigned)f2bf(pm(mm[1], ap)) << 16),
                            (unsigned)f2bf(pm(mm[2], ap)) | ((unsigned)f2bf(pm(mm[3], ap)) << 16)};
                *(uint2*)(XtOut + nb) = px;
            }
        }
    }
}

// ---------------------------------------------------------------------------
extern "C" void kernel_launch(void* const* d_in, const int* in_sizes, int n_in,
                              void* d_out, int out_size, void* d_ws, size_t ws_size,
                              hipStream_t stream)
{
    const float* x  = (const float*)d_in[0];
    const float* w1 = (const float*)d_in[1];
    const float* b1 = (const float*)d_in[2];
    const float* w2 = (const float*)d_in[3];
    const float* b2 = (const float*)d_in[4];
    const float* w3 = (const float*)d_in[5];
    const float* b3 = (const float*)d_in[6];
    const float* pa = (const float*)d_in[7];

    char* ws = (char*)d_ws;
    ushort* Xt1  = (ushort*)ws;                       // 67108864 B (bf16 NHWC)
    ushort* Xt2  = (ushort*)(ws + 67108864);          // 67108864 B (bf16 NHWC)
    ushort* xmax = (ushort*)(ws + 134217728);         // 67108864 B (bf16 NHWC)
    ushort* Wtf  = (ushort*)(ws + 201326592);         // 3 x 1179648 B

    // opt-in to >64KB dynamic LDS for the conv kernels (once per process)
    static bool attr_done = false;
    if (!attr_done) {
        hipFuncSetAttribute((const void*)conv_kernel<0>,
                            hipFuncAttributeMaxDynamicSharedMemorySize, SA_BYTES);
        hipFuncSetAttribute((const void*)conv_kernel<1>,
                            hipFuncAttributeMaxDynamicSharedMemorySize, SA_BYTES);
        hipFuncSetAttribute((const void*)conv_kernel<2>,
                            hipFuncAttributeMaxDynamicSharedMemorySize, SA_BYTES);
        attr_done = true;
    }

    dim3 tg(4, 128, 8), tb(256);

    wtrans_kernel<<<dim3(256, 1, 3), 256, 0, stream>>>(w1, w2, w3, Wtf);
    // Xt1 = pm(x)  (NHWC bf16)
    xt1_kernel<<<tg, tb, 0, stream>>>(x, pa, Xt1);
    // conv1 + fused max/prelu/mask/transpose: xmax = max(x, conv1), Xt2 = pm(xmax)
    conv_kernel<1><<<dim3(2048), tb, SA_BYTES, stream>>>(Xt1, Wtf, b1, pa, x, xmax, Xt2, nullptr);
    // conv2 + fused: Xt1 (dead, reused) = pm(max(conv2, xmax))
    conv_kernel<2><<<dim3(2048), tb, SA_BYTES, stream>>>(Xt2, Wtf + WSZ, b2, pa, nullptr, xmax, Xt1, nullptr);
    // conv3 -> fp32 out
    conv_kernel<0><<<dim3(2048), tb, SA_BYTES, stream>>>(Xt1, Wtf + 2 * WSZ, b3, pa, nullptr, nullptr, nullptr, (float*)d_out);
}